// Round 4
// baseline (134.341 us; speedup 1.0000x reference)
//
#include <hip/hip_runtime.h>

typedef unsigned short u16;
typedef unsigned int   u32;
typedef short  short8  __attribute__((ext_vector_type(8)));
typedef __bf16 bf16x8  __attribute__((ext_vector_type(8)));
typedef float  f32x4   __attribute__((ext_vector_type(4)));
typedef u32    u32x4   __attribute__((ext_vector_type(4)));

#define POWER_ITERS 3

// ---------- helpers ----------
__device__ __forceinline__ u16 f2bf(float f){ return __builtin_bit_cast(u16, (__bf16)f); }
__device__ __forceinline__ u32 pack2bf(float a, float b){
  return (u32)__builtin_bit_cast(u16, (__bf16)a) | ((u32)__builtin_bit_cast(u16, (__bf16)b) << 16);
}
__device__ __forceinline__ float bf2f(u16 h){ return __uint_as_float(((u32)h) << 16); }

__device__ __forceinline__ f32x4 mfma_bf16(short8 a, short8 b, f32x4 c){
  return __builtin_amdgcn_mfma_f32_16x16x32_bf16(
      __builtin_bit_cast(bf16x8, a), __builtin_bit_cast(bf16x8, b), c, 0, 0, 0);
}

// swizzled LDS address (u16 units) of element [row][k] of a 64x64 matrix
__device__ __forceinline__ int swz(int row, int k){
  return row*64 + ((((k >> 3) ^ (row & 7)) << 3) | (k & 7));
}
__device__ __forceinline__ short8 lds_frag(const u16* P, int row, int k0){
  int pos = (k0 >> 3) ^ (row & 7);
  return *(const short8*)(P + row*64 + pos*8);
}
__device__ __forceinline__ short8 g_frag(const u16* __restrict__ M, int row, int k0){
  return *(const short8*)(M + row*64 + k0);
}

// write C/D regs (matrix X) as X^T into swizzled LDS (Zt), scaled
__device__ __forceinline__ void write_CT_lds_s(u16* Pt, int lane, const f32x4 (&C)[4][4], float s){
  const int m16 = lane & 15, q = lane >> 4;
#pragma unroll
  for(int i = 0; i < 4; i++){
    const int r0 = i*16 + q*4;
#pragma unroll
    for(int j = 0; j < 4; j++){
      const int c = j*16 + m16;
      const int addr = c*64 + ((((r0 >> 3) ^ (c & 7)) << 3) | (r0 & 7));
      u32 lo = pack2bf(C[i][j][0]*s, C[i][j][1]*s);
      u32 hi = pack2bf(C[i][j][2]*s, C[i][j][3]*s);
      *(uint2*)(Pt + addr) = make_uint2(lo, hi);
    }
  }
}
__device__ __forceinline__ void write_CT_lds(u16* Pt, int lane, const f32x4 (&C)[4][4]){
  write_CT_lds_s(Pt, lane, C, 1.f);
}

// write C ROW-MAJOR swizzled (Zn), scaled — scalar scatter
__device__ __forceinline__ void scatter_C_rm(u16* Z, int lane, const f32x4 (&C)[4][4], float s){
  const int m16 = lane & 15, q = lane >> 4;
#pragma unroll
  for(int i = 0; i < 4; i++)
#pragma unroll
    for(int j = 0; j < 4; j++)
#pragma unroll
      for(int t = 0; t < 4; t++)
        Z[swz(i*16 + q*4 + t, j*16 + m16)] = f2bf(C[i][j][t]*s);
}

// C = A (regs) * P (Pt = Zt of P); optional writeback of C^T into Pt (in-wave safe)
__device__ __forceinline__ void chain_step_A(const short8 (&Af)[2][4], u16* Pt, int lane,
                                             f32x4 (&C)[4][4], bool wb){
  const int m16 = lane & 15, q = lane >> 4;
  short8 Bf[2][4];
#pragma unroll
  for(int ks = 0; ks < 2; ks++)
#pragma unroll
    for(int t = 0; t < 4; t++) Bf[ks][t] = lds_frag(Pt, t*16 + m16, ks*32 + q*8);
#pragma unroll
  for(int i = 0; i < 4; i++)
#pragma unroll
    for(int j = 0; j < 4; j++) C[i][j] = f32x4{0.f,0.f,0.f,0.f};
#pragma unroll
  for(int ks = 0; ks < 2; ks++)
#pragma unroll
    for(int i = 0; i < 4; i++)
#pragma unroll
      for(int j = 0; j < 4; j++)
        C[i][j] = mfma_bf16(Af[ks][i], Bf[ks][j], C[i][j]);
  if(wb) write_CT_lds(Pt, lane, C);
}

__device__ __forceinline__ void ld_zn_frags(const u16* Zn, int m16, int q, short8 (&Af)[2][4]){
#pragma unroll
  for(int ks = 0; ks < 2; ks++)
#pragma unroll
    for(int t = 0; t < 4; t++) Af[ks][t] = lds_frag(Zn, t*16 + m16, ks*32 + q*8);
}
__device__ __forceinline__ void ld_bf16_frags(const u16* __restrict__ M, int m16, int q, short8 (&Af)[2][4]){
#pragma unroll
  for(int ks = 0; ks < 2; ks++)
#pragma unroll
    for(int t = 0; t < 4; t++) Af[ks][t] = g_frag(M, t*16 + m16, ks*32 + q*8);
}

// A-frags of K_a straight from global fp32 (identical bf16 conversion to LDS staging).
// NOTE: these same registers serve as B-frags of K_a^T (A-pattern of X == B-pattern of X^T).
__device__ __forceinline__ void ld_gK_frags(const float* __restrict__ Kp, int m16, int q, short8 (&Af)[2][4]){
#pragma unroll
  for(int ks = 0; ks < 2; ks++)
#pragma unroll
    for(int t = 0; t < 4; t++){
      const float* p = Kp + (t*16 + m16)*64 + ks*32 + q*8;
      float4 a = *(const float4*)p, c = *(const float4*)(p + 4);
      short8 v;
      v[0]=(short)f2bf(a.x); v[1]=(short)f2bf(a.y); v[2]=(short)f2bf(a.z); v[3]=(short)f2bf(a.w);
      v[4]=(short)f2bf(c.x); v[5]=(short)f2bf(c.y); v[6]=(short)f2bf(c.z); v[7]=(short)f2bf(c.w);
      Af[ks][t] = v;
    }
}
// frags of K_a^T (column gather; one-time, L2-hot)
__device__ __forceinline__ void ld_gKT_frags(const float* __restrict__ Kp, int m16, int q, short8 (&Af)[2][4]){
#pragma unroll
  for(int ks = 0; ks < 2; ks++)
#pragma unroll
    for(int t = 0; t < 4; t++){
      short8 v;
#pragma unroll
      for(int e = 0; e < 8; e++) v[e] = (short)f2bf(Kp[(ks*32 + q*8 + e)*64 + t*16 + m16]);
      Af[ks][t] = v;
    }
}

// P = N (global row-major bf16) -> Zt of P
__device__ __forceinline__ void load_Pt_transpose(const u16* __restrict__ N, u16* Pt, int lane){
#pragma unroll
  for(int g = 0; g < 8; g++){
    short8 v = *(const short8*)(N + lane*64 + g*8);
#pragma unroll
    for(int t = 0; t < 8; t++) Pt[swz(g*8 + t, lane)] = (u16)v[t];
  }
}
// Pt <- Zt of an LDS Zn zone
__device__ __forceinline__ void lds_transpose(const u16* Z, u16* Pt, int lane){
#pragma unroll
  for(int g = 0; g < 8; g++){
    short8 f = lds_frag(Z, lane, g*8);
#pragma unroll
    for(int j = 0; j < 8; j++) Pt[swz(g*8 + j, lane)] = (u16)f[j];
  }
}

__device__ __forceinline__ float wave_max(float mx){
  for(int off = 32; off; off >>= 1) mx = fmaxf(mx, __shfl_xor(mx, off, 64));
  return mx;
}
__device__ __forceinline__ int norm_es(const f32x4 (&C)[4][4], float& s){
  float mx = 0.f;
#pragma unroll
  for(int i = 0; i < 4; i++)
#pragma unroll
    for(int j = 0; j < 4; j++)
#pragma unroll
      for(int t = 0; t < 4; t++) mx = fmaxf(mx, C[i][j][t]);   // entries all positive
  mx = wave_max(mx);
  int e; (void)frexpf(mx, &e);
  s = ldexpf(1.f, -e);
  return e;
}

// store a 64x64 node from LDS (Zn swizzled) to global row-major; ONE WAVE (lane = row)
__device__ __forceinline__ void store_node_wave(const u16* Z, u16* __restrict__ out, int lane){
#pragma unroll
  for(int g = 0; g < 8; g++){
    short8 v = lds_frag(Z, lane, g*8);
    *(short8*)(out + lane*64 + g*8) = v;
  }
}

// ==================== K1: 512 blocks x 512 threads, 2 blocks/CU ====================
// Blocks != {0,256}: chain block. 8 waves stage K into LDS, 7 exit, wave 0 chains
// 32-33 seq mats (renorm every 8; exact 2^-e scale). 510 chains cover 16384.
// Blocks 0 (right) / 256 (left): power iteration; K frags from global (no Kl),
// zones overlay the Kl area; numerics identical to the verified R3 power code.
__global__ void __launch_bounds__(512, 4) k1(const float* __restrict__ K, const int* __restrict__ seq,
                                             u16* __restrict__ Nbuf, int* __restrict__ Sarr,
                                             float* __restrict__ rhoR, float* __restrict__ rhoL,
                                             float* __restrict__ muv){
  __shared__ __align__(16) u16 KlZ[9*4096];   // chain: Kl[8]+zone | power: zones[8]+rhoZ
  __shared__ float redf[8];
  const int tid = threadIdx.x, lane = tid & 63, wave = tid >> 6, b = blockIdx.x;
  const int m16 = lane & 15, q = lane >> 4;

  if(b != 0 && b != 256){
    // ---------------- chain block ----------------
    u16* Kl = KlZ;
    u16* zone = KlZ + 8*4096;
    // stage K[wave] fp32 -> Kl (Zn swizzled); lane owns row = lane
#pragma unroll
    for(int g = 0; g < 8; g++){
      const float* p = K + (size_t)wave*4096 + lane*64 + g*8;
      float4 a = *(const float4*)p, c = *(const float4*)(p + 4);
      u32x4 u = { pack2bf(a.x,a.y), pack2bf(a.z,a.w), pack2bf(c.x,c.y), pack2bf(c.z,c.w) };
      *(short8*)(Kl + wave*4096 + lane*64 + ((g ^ (lane & 7)) << 3)) = __builtin_bit_cast(short8, u);
    }
    const int c = b - 1 - (b > 256);           // 0..509
    const int len = 32 + (c < 64 ? 1 : 0);     // 64x33 + 446x32 = 16384
    const int start = c*32 + (c < 64 ? c : 64);
    int sv = (lane < len) ? seq[start + lane] : 0;
    __syncthreads();
    if(wave) return;                            // no barriers after this point

    int s0 = __shfl(sv, 0, 64);
    lds_transpose(Kl + s0*4096, zone, lane);
    f32x4 C[4][4];
    short8 Af[2][4];
    int ew = 0;
#pragma unroll 1
    for(int j = 1; j < len; j++){
      int sj = __shfl(sv, j, 64);
      ld_zn_frags(Kl + sj*4096, m16, q, Af);
      chain_step_A(Af, zone, lane, C, false);
      if(j == len - 1) break;                   // last: keep in regs
      if((j & 7) == 7){ float s; ew += norm_es(C, s); write_CT_lds_s(zone, lane, C, s); }
      else write_CT_lds(zone, lane, C);
    }
    { float s; ew += norm_es(C, s);
      scatter_C_rm(zone, lane, C, s); }         // Zn row-major swizzled
    store_node_wave(zone, Nbuf + (size_t)c*4096, lane);
    if(lane == 0) Sarr[c] = ew;
    return;
  }

  // ---------------- power block (b==0 right, b==256 left) ----------------
  const bool left = (b == 256);
  u16* zones = KlZ;
  u16* rhoZ  = KlZ + 8*4096;
  u16* zw = zones + wave*4096;
  short8 Kf[2][4];                              // dual-use: A-frags of K_a AND B-frags of K_a^T
  if(!left) ld_gK_frags (K + (size_t)wave*4096, m16, q, Kf);
  else      ld_gKT_frags(K + (size_t)wave*4096, m16, q, Kf);

  const int row = tid >> 3, k0 = (tid & 7)*8;
  const int rpos = row*64 + (((tid & 7) ^ (row & 7)) << 3);
  {
    short8 bb;
#pragma unroll
    for(int j = 0; j < 8; j++) bb[j] = (row == k0 + j) ? (short)f2bf(1.f/64.f) : (short)0;
    *(short8*)(rhoZ + rpos) = bb;
  }
  __syncthreads();
  const float S13 = 1.f/8192.f;        // fixed per-iter scale (lambda ~ 2^13)
#pragma unroll
  for(int it = 0; it < POWER_ITERS; it++){
    short8 Ar[2][4];
#pragma unroll
    for(int ks = 0; ks < 2; ks++)
#pragma unroll
      for(int t = 0; t < 4; t++) Ar[ks][t] = lds_frag(rhoZ, t*16 + m16, ks*32 + q*8);
    f32x4 C[4][4];
#pragma unroll
    for(int i = 0; i < 4; i++)
#pragma unroll
      for(int j = 0; j < 4; j++) C[i][j] = f32x4{0.f,0.f,0.f,0.f};
#pragma unroll
    for(int ks = 0; ks < 2; ks++)
#pragma unroll
      for(int i = 0; i < 4; i++)
#pragma unroll
        for(int j = 0; j < 4; j++)
          C[i][j] = mfma_bf16(Ar[ks][i], Kf[ks][j], C[i][j]);   // rho * Kdir^T
    write_CT_lds(zw, lane, C);
    short8 Bt[2][4];
#pragma unroll
    for(int ks = 0; ks < 2; ks++)
#pragma unroll
      for(int t = 0; t < 4; t++) Bt[ks][t] = lds_frag(zw, t*16 + m16, ks*32 + q*8);
#pragma unroll
    for(int i = 0; i < 4; i++)
#pragma unroll
      for(int j = 0; j < 4; j++) C[i][j] = f32x4{0.f,0.f,0.f,0.f};
#pragma unroll
    for(int ks = 0; ks < 2; ks++)
#pragma unroll
      for(int i = 0; i < 4; i++)
#pragma unroll
        for(int j = 0; j < 4; j++)
          C[i][j] = mfma_bf16(Kf[ks][i], Bt[ks][j], C[i][j]);   // Kdir * (..)^T
    write_CT_lds(zw, lane, C);
    __syncthreads();
    float v[8];
#pragma unroll
    for(int j2 = 0; j2 < 8; j2++) v[j2] = 0.f;
#pragma unroll
    for(int z = 0; z < 8; z++){
      short8 f = lds_frag(zones + z*4096, row, k0);
#pragma unroll
      for(int j2 = 0; j2 < 8; j2++) v[j2] += bf2f((u16)f[j2]);
    }
    if(it != POWER_ITERS - 1){
      u32x4 u = { pack2bf(v[0]*S13, v[1]*S13), pack2bf(v[2]*S13, v[3]*S13),
                  pack2bf(v[4]*S13, v[5]*S13), pack2bf(v[6]*S13, v[7]*S13) };
      *(short8*)(rhoZ + rpos) = __builtin_bit_cast(short8, u);
      __syncthreads();
    } else {
      float pd = (k0 <= row && row < k0 + 8) ? v[row - k0] : 0.f;
      for(int off = 32; off; off >>= 1) pd += __shfl_xor(pd, off, 64);
      if(lane == 0) redf[wave] = pd;
      __syncthreads();
      float tr = 0.f;
#pragma unroll
      for(int w = 0; w < 8; w++) tr += redf[w];
      float inv = 1.f/tr;
      float* ro = left ? rhoL : rhoR;
      f32x4 w0 = { v[0]*inv, v[1]*inv, v[2]*inv, v[3]*inv };
      f32x4 w1 = { v[4]*inv, v[5]*inv, v[6]*inv, v[7]*inv };
      *(f32x4*)(ro + row*64 + k0)     = w0;
      *(f32x4*)(ro + row*64 + k0 + 4) = w1;
      u32x4 u = { pack2bf(v[0]*inv, v[1]*inv), pack2bf(v[2]*inv, v[3]*inv),
                  pack2bf(v[4]*inv, v[5]*inv), pack2bf(v[6]*inv, v[7]*inv) };
      *(short8*)(rhoZ + rpos) = __builtin_bit_cast(short8, u);   // normalized bf16 in LDS
      __syncthreads();
    }
  }
  if(left){
    // lambda = tr(rho_l * sum_a K_a K_a^T); wave a handles K_a
    short8 Ka[2][4];
    ld_gK_frags(K + (size_t)wave*4096, m16, q, Ka);
    f32x4 G[4][4];
#pragma unroll
    for(int i = 0; i < 4; i++)
#pragma unroll
      for(int j = 0; j < 4; j++) G[i][j] = f32x4{0.f,0.f,0.f,0.f};
#pragma unroll
    for(int ks = 0; ks < 2; ks++)
#pragma unroll
      for(int i = 0; i < 4; i++)
#pragma unroll
        for(int j = 0; j < 4; j++)
          G[i][j] = mfma_bf16(Ka[ks][i], Ka[ks][j], G[i][j]);
    float lp = 0.f;
#pragma unroll
    for(int i = 0; i < 4; i++)
#pragma unroll
      for(int j = 0; j < 4; j++)
#pragma unroll
        for(int t = 0; t < 4; t++){
          int r = i*16 + q*4 + t, c = j*16 + m16;
          lp += G[i][j][t] * bf2f(rhoZ[swz(r, c)]);
        }
    for(int off = 32; off; off >>= 1) lp += __shfl_xor(lp, off, 64);
    if(lane == 0) redf[wave] = lp;
    __syncthreads();
    if(tid == 0){
      float m = 0.f;
#pragma unroll
      for(int w = 0; w < 8; w++) m += redf[w];
      muv[0] = m;
    }
  }
}

// ==================== k_red: single-wave blocks, chain up to 8 nodes -> 1 ====================
// block b: nodes [b*8, min(b*8+8, total)); Eout[b] = own norm exp + sum of children's.
__global__ void __launch_bounds__(64) k_red(const u16* __restrict__ in, const int* __restrict__ Ein,
                                            u16* __restrict__ out, int* __restrict__ Eout, int total){
  __shared__ __align__(16) u16 zone[4096];
  const int lane = threadIdx.x & 63, b = blockIdx.x;
  const int m16 = lane & 15, q = lane >> 4;
  const int n0 = b*8;
  const int cnt = min(8, total - n0);

  load_Pt_transpose(in + (size_t)n0*4096, zone, lane);
  f32x4 C[4][4];
  short8 Af[2][4];
#pragma unroll 1
  for(int j = 1; j < cnt; j++){
    ld_bf16_frags(in + (size_t)(n0 + j)*4096, m16, q, Af);
    chain_step_A(Af, zone, lane, C, j < cnt - 1);
  }
  float s; int e = norm_es(C, s);
  scatter_C_rm(zone, lane, C, s);
  store_node_wave(zone, out + (size_t)b*4096, lane);
  int sacc = (lane < cnt) ? Ein[n0 + lane] : 0;
  for(int off = 32; off; off >>= 1) sacc += __shfl_xor(sacc, off, 64);
  if(lane == 0) Eout[b] = e + sacc;
}

// ==================== K4: 1 block x 1 wave — chain 8 + contraction ====================
__global__ void __launch_bounds__(64) k4(const u16* __restrict__ M3, const int* __restrict__ E3,
                                         const float* __restrict__ rhoR, const float* __restrict__ rhoL,
                                         const float* __restrict__ muv, float* __restrict__ outp){
  __shared__ __align__(16) u16 Z[5*4096];  // 0: chain zone, 1: Pm (M Zn), 2: U^T, 3: rhoL Zn, 4: rhoR Zn
  const int lane = threadIdx.x & 63;
  const int m16 = lane & 15, q = lane >> 4;
  u16* zone = Z;
  u16* Pm   = Z + 4096;
  u16* z2   = Z + 2*4096;
  u16* zl   = Z + 3*4096;
  u16* zr   = Z + 4*4096;

  // chain the 8 level-3 nodes
  load_Pt_transpose(M3, zone, lane);
  f32x4 C[4][4];
  short8 Af[2][4];
#pragma unroll 1
  for(int j = 1; j < 8; j++){
    ld_bf16_frags(M3 + (size_t)j*4096, m16, q, Af);
    chain_step_A(Af, zone, lane, C, j < 7);
  }
  float sM; int eM = norm_es(C, sM);
  scatter_C_rm(Pm, lane, C, sM);               // M (Zn)

  // stage rho_r / rho_l fp32 -> Zn bf16 (lane owns row = lane)
#pragma unroll
  for(int g = 0; g < 8; g++){
    const float* p = rhoR + lane*64 + g*8;
    float4 a = *(const float4*)p, c = *(const float4*)(p + 4);
    u32x4 u = { pack2bf(a.x,a.y), pack2bf(a.z,a.w), pack2bf(c.x,c.y), pack2bf(c.z,c.w) };
    *(short8*)(zr + lane*64 + ((g ^ (lane & 7)) << 3)) = __builtin_bit_cast(short8, u);
  }
#pragma unroll
  for(int g = 0; g < 8; g++){
    const float* p = rhoL + lane*64 + g*8;
    float4 a = *(const float4*)p, c = *(const float4*)(p + 4);
    u32x4 u = { pack2bf(a.x,a.y), pack2bf(a.z,a.w), pack2bf(c.x,c.y), pack2bf(c.z,c.w) };
    *(short8*)(zl + lane*64 + ((g ^ (lane & 7)) << 3)) = __builtin_bit_cast(short8, u);
  }

  // t2 = sum rho_r o rho_l (fp32, from global)
  float t2 = 0.f;
  for(int j = 0; j < 64; j++){
    int idx = lane + 64*j;
    t2 += rhoR[idx] * rhoL[idx];
  }
  for(int off = 32; off; off >>= 1) t2 += __shfl_xor(t2, off, 64);

  // S = sum E3 + eM
  int sacc = (lane < 8) ? E3[lane] : 0;
  for(int off = 32; off; off >>= 1) sacc += __shfl_xor(sacc, off, 64);

  // U = M * rho_r -> U^T in z2   (rho symmetric: Zn A-pattern reads == B-frags)
  short8 Ua[2][4], Ub[2][4];
  ld_zn_frags(Pm, m16, q, Ua);
  ld_zn_frags(zr, m16, q, Ub);
#pragma unroll
  for(int i = 0; i < 4; i++)
#pragma unroll
    for(int j = 0; j < 4; j++) C[i][j] = f32x4{0.f,0.f,0.f,0.f};
#pragma unroll
  for(int ks = 0; ks < 2; ks++)
#pragma unroll
    for(int i = 0; i < 4; i++)
#pragma unroll
      for(int j = 0; j < 4; j++)
        C[i][j] = mfma_bf16(Ua[ks][i], Ub[ks][j], C[i][j]);
  write_CT_lds(z2, lane, C);

  // D2 = rho_l * U
  ld_zn_frags(zl, m16, q, Ua);
#pragma unroll
  for(int ks = 0; ks < 2; ks++)
#pragma unroll
    for(int t = 0; t < 4; t++) Ub[ks][t] = lds_frag(z2, t*16 + m16, ks*32 + q*8);
#pragma unroll
  for(int i = 0; i < 4; i++)
#pragma unroll
    for(int j = 0; j < 4; j++) C[i][j] = f32x4{0.f,0.f,0.f,0.f};
#pragma unroll
  for(int ks = 0; ks < 2; ks++)
#pragma unroll
    for(int i = 0; i < 4; i++)
#pragma unroll
      for(int j = 0; j < 4; j++)
        C[i][j] = mfma_bf16(Ua[ks][i], Ub[ks][j], C[i][j]);

  // t1 = sum_ij D2_ij * M_ij
  float part = 0.f;
#pragma unroll
  for(int i = 0; i < 4; i++)
#pragma unroll
    for(int j = 0; j < 4; j++)
#pragma unroll
      for(int t = 0; t < 4; t++){
        int r = i*16 + q*4 + t, c = j*16 + m16;
        part += C[i][j][t] * bf2f(Pm[swz(r, c)]);
      }
  for(int off = 32; off; off >>= 1) part += __shfl_xor(part, off, 64);
  if(lane == 0){
    double t1  = (double)part;
    double lam = (double)muv[0];
    double S   = (double)sacc + eM;
    double logp = 16384.0*log2(lam) - 2.0*S - log2(t1) + log2((double)t2);
    outp[0] = (float)logp;
  }
}

// ---------- launch: four stream-ordered kernels ----------
extern "C" void kernel_launch(void* const* d_in, const int* in_sizes, int n_in,
                              void* d_out, int out_size, void* d_ws, size_t ws_size,
                              hipStream_t stream) {
  const float* K  = (const float*)d_in[0];   // (8,64,64) fp32
  const int* seq  = (const int*)d_in[1];     // (16384,) int32
  char* ws = (char*)d_ws;
  u16*   Nbuf = (u16*)(ws);                    // 510 * 8KB = 4,177,920
  u16*   M2   = (u16*)(ws + 4177920);          // 64 * 8KB
  u16*   M3   = (u16*)(ws + 4702208);          // 8 * 8KB
  int*   Sarr = (int*)(ws + 4767744);          // 510 ints
  int*   E2   = (int*)(ws + 4771840);          // 64 ints
  int*   E3   = (int*)(ws + 4772096);          // 8 ints
  float* rhoR = (float*)(ws + 4772352);        // 16 KB
  float* rhoL = (float*)(ws + 4788736);        // 16 KB
  float* muv  = (float*)(ws + 4805120);        // 1 float

  k1   <<<512, 512, 0, stream>>>(K, seq, Nbuf, Sarr, rhoR, rhoL, muv);
  k_red<<< 64,  64, 0, stream>>>(Nbuf, Sarr, M2, E2, 510);
  k_red<<<  8,  64, 0, stream>>>(M2, E2, M3, E3, 64);
  k4   <<<  1,  64, 0, stream>>>(M3, E3, rhoR, rhoL, muv, (float*)d_out);
}

// Round 5
// 119.252 us; speedup vs baseline: 1.1265x; 1.1265x over previous
//
#include <hip/hip_runtime.h>

typedef unsigned short u16;
typedef unsigned int   u32;
typedef short  short8  __attribute__((ext_vector_type(8)));
typedef __bf16 bf16x8  __attribute__((ext_vector_type(8)));
typedef float  f32x4   __attribute__((ext_vector_type(4)));
typedef u32    u32x4   __attribute__((ext_vector_type(4)));

#define POWER_ITERS 3

// ---------- helpers ----------
__device__ __forceinline__ u16 f2bf(float f){ return __builtin_bit_cast(u16, (__bf16)f); }
__device__ __forceinline__ u32 pack2bf(float a, float b){
  return (u32)__builtin_bit_cast(u16, (__bf16)a) | ((u32)__builtin_bit_cast(u16, (__bf16)b) << 16);
}
__device__ __forceinline__ float bf2f(u16 h){ return __uint_as_float(((u32)h) << 16); }

__device__ __forceinline__ f32x4 mfma_bf16(short8 a, short8 b, f32x4 c){
  return __builtin_amdgcn_mfma_f32_16x16x32_bf16(
      __builtin_bit_cast(bf16x8, a), __builtin_bit_cast(bf16x8, b), c, 0, 0, 0);
}

// swizzled LDS address (u16 units) of element [row][k] of a 64x64 matrix
__device__ __forceinline__ int swz(int row, int k){
  return row*64 + ((((k >> 3) ^ (row & 7)) << 3) | (k & 7));
}
__device__ __forceinline__ short8 lds_frag(const u16* P, int row, int k0){
  int pos = (k0 >> 3) ^ (row & 7);
  return *(const short8*)(P + row*64 + pos*8);
}
__device__ __forceinline__ short8 g_frag(const u16* __restrict__ M, int row, int k0){
  return *(const short8*)(M + row*64 + k0);
}

// exact frexpf-exponent for normal positive floats, and 2^k builder
__device__ __forceinline__ int expof(float x){ return (int)(__float_as_uint(x) >> 23) - 126; }
__device__ __forceinline__ float exp2i(int k){ return __uint_as_float((u32)(127 + k) << 23); }

__device__ __forceinline__ float wave_max(float mx){
  for(int off = 32; off; off >>= 1) mx = fmaxf(mx, __shfl_xor(mx, off, 64));
  return mx;
}

// ---------- full-matrix helpers (power blocks + k4 contraction) ----------
__device__ __forceinline__ void write_CT_lds_s(u16* Pt, int lane, const f32x4 (&C)[4][4], float s){
  const int m16 = lane & 15, q = lane >> 4;
#pragma unroll
  for(int i = 0; i < 4; i++){
    const int r0 = i*16 + q*4;
#pragma unroll
    for(int j = 0; j < 4; j++){
      const int c = j*16 + m16;
      const int addr = c*64 + ((((r0 >> 3) ^ (c & 7)) << 3) | (r0 & 7));
      u32 lo = pack2bf(C[i][j][0]*s, C[i][j][1]*s);
      u32 hi = pack2bf(C[i][j][2]*s, C[i][j][3]*s);
      *(uint2*)(Pt + addr) = make_uint2(lo, hi);
    }
  }
}
__device__ __forceinline__ void write_CT_lds(u16* Pt, int lane, const f32x4 (&C)[4][4]){
  write_CT_lds_s(Pt, lane, C, 1.f);
}
__device__ __forceinline__ void ld_zn_frags(const u16* Zn, int m16, int q, short8 (&Af)[2][4]){
#pragma unroll
  for(int ks = 0; ks < 2; ks++)
#pragma unroll
    for(int t = 0; t < 4; t++) Af[ks][t] = lds_frag(Zn, t*16 + m16, ks*32 + q*8);
}
__device__ __forceinline__ void ld_bf16_frags(const u16* __restrict__ M, int m16, int q, short8 (&Af)[2][4]){
#pragma unroll
  for(int ks = 0; ks < 2; ks++)
#pragma unroll
    for(int t = 0; t < 4; t++) Af[ks][t] = g_frag(M, t*16 + m16, ks*32 + q*8);
}
// A-frags of K_a from global fp32 (same bf16 conversion as staging)
__device__ __forceinline__ void ld_gK_frags(const float* __restrict__ Kp, int m16, int q, short8 (&Af)[2][4]){
#pragma unroll
  for(int ks = 0; ks < 2; ks++)
#pragma unroll
    for(int t = 0; t < 4; t++){
      const float* p = Kp + (t*16 + m16)*64 + ks*32 + q*8;
      float4 a = *(const float4*)p, c = *(const float4*)(p + 4);
      short8 v;
      v[0]=(short)f2bf(a.x); v[1]=(short)f2bf(a.y); v[2]=(short)f2bf(a.z); v[3]=(short)f2bf(a.w);
      v[4]=(short)f2bf(c.x); v[5]=(short)f2bf(c.y); v[6]=(short)f2bf(c.z); v[7]=(short)f2bf(c.w);
      Af[ks][t] = v;
    }
}
// frags of K_a^T (column gather; one-time, L2-hot)
__device__ __forceinline__ void ld_gKT_frags(const float* __restrict__ Kp, int m16, int q, short8 (&Af)[2][4]){
#pragma unroll
  for(int ks = 0; ks < 2; ks++)
#pragma unroll
    for(int t = 0; t < 4; t++){
      short8 v;
#pragma unroll
      for(int e = 0; e < 8; e++) v[e] = (short)f2bf(Kp[(ks*32 + q*8 + e)*64 + t*16 + m16]);
      Af[ks][t] = v;
    }
}

// ---------- slice (16-column) chain primitives: wave w owns cols [w*16, w*16+16) ----------
__device__ __forceinline__ void ldKfrag(short8 (&Af)[2][4], const u16* __restrict__ Kf, int a, int lane){
#pragma unroll
  for(int ks = 0; ks < 2; ks++)
#pragma unroll
    for(int t = 0; t < 4; t++)
      Af[ks][t] = *(const short8*)(Kf + (size_t)((a*8 + ks*4 + t)*64 + lane)*8);
}
__device__ __forceinline__ void slice_mfma(const short8 (&Af)[2][4], const u16* Pt, int w,
                                           int m16, int q, f32x4 (&C)[4]){
  short8 b0 = lds_frag(Pt, w*16 + m16, q*8);
  short8 b1 = lds_frag(Pt, w*16 + m16, 32 + q*8);
#pragma unroll
  for(int i = 0; i < 4; i++) C[i] = f32x4{0.f,0.f,0.f,0.f};
#pragma unroll
  for(int i = 0; i < 4; i++) C[i] = mfma_bf16(Af[0][i], b0, C[i]);
#pragma unroll
  for(int i = 0; i < 4; i++) C[i] = mfma_bf16(Af[1][i], b1, C[i]);
}
__device__ __forceinline__ void write_CT_slice(u16* Pt, int w, int m16, int q,
                                               const f32x4 (&C)[4], float s){
  const int c = w*16 + m16;
#pragma unroll
  for(int i = 0; i < 4; i++){
    const int r0 = i*16 + q*4;
    const int addr = c*64 + ((((r0 >> 3) ^ (c & 7)) << 3) | (r0 & 7));
    *(uint2*)(Pt + addr) = make_uint2(pack2bf(C[i][0]*s, C[i][1]*s),
                                      pack2bf(C[i][2]*s, C[i][3]*s));
  }
}
__device__ __forceinline__ void scatter_slice(u16* Z, int w, int m16, int q,
                                              const f32x4 (&C)[4], float s){
#pragma unroll
  for(int i = 0; i < 4; i++)
#pragma unroll
    for(int t = 0; t < 4; t++)
      Z[swz(i*16 + q*4 + t, w*16 + m16)] = f2bf(C[i][t]*s);
}
__device__ __forceinline__ float slice_max(const f32x4 (&C)[4]){
  float mx = 0.f;
#pragma unroll
  for(int i = 0; i < 4; i++)
#pragma unroll
    for(int t = 0; t < 4; t++) mx = fmaxf(mx, C[i][t]);   // entries positive
  return wave_max(mx);
}

// store a 64x64 node from LDS (Zn swizzled) to global, 512 threads
__device__ __forceinline__ void store_node(const u16* Z, u16* __restrict__ out, int tid){
  int row = tid >> 3, c0 = (tid & 7)*8;
  short8 v = lds_frag(Z, row, c0);
  *(short8*)(out + row*64 + c0) = v;
}

// ==================== kprep: build Kfrag (bf16 A-frag table, 64 KB) ====================
__global__ void __launch_bounds__(512) kprep(const float* __restrict__ K, u16* __restrict__ Kfrag){
  const int tid = threadIdx.x, lane = tid & 63, a = tid >> 6;
  const int m16 = lane & 15, q = lane >> 4;
  short8 Af[2][4];
  ld_gK_frags(K + (size_t)a*4096, m16, q, Af);
#pragma unroll
  for(int ks = 0; ks < 2; ks++)
#pragma unroll
    for(int t = 0; t < 4; t++)
      *(short8*)(Kfrag + (size_t)((a*8 + ks*4 + t)*64 + lane)*8) = Af[ks][t];
}

// ==================== K1: 512 blocks x 512 threads ====================
// Blocks 0 (right) / 1 (left): power iteration (verbatim R4, 8 waves, zones in LDS).
// Blocks 2..511: chain c = b-2 over 32-33 seq mats; waves 0-3 each own a 16-col slice
// (independent chains, per-slice renorm exponents, unified at the node boundary —
// bit-identical to global renorm since all scales are powers of 2). Waves 4-7 idle
// through the 2 barriers and help store. A-frags double-buffered from Kfrag (L2-hot).
__global__ void __launch_bounds__(512) k1(const float* __restrict__ K, const u16* __restrict__ Kfrag,
                                          const int* __restrict__ seq,
                                          u16* __restrict__ Nbuf, int* __restrict__ Sarr,
                                          float* __restrict__ rhoR, float* __restrict__ rhoL,
                                          float* __restrict__ muv){
  __shared__ __align__(16) u16 KlZ[9*4096];   // chain: zone = first 4096 | power: zones[8]+rhoZ
  __shared__ float redf[8];
  __shared__ int exps[4];
  const int tid = threadIdx.x, lane = tid & 63, wave = tid >> 6, b = blockIdx.x;
  const int m16 = lane & 15, q = lane >> 4;

  if(b >= 2){
    // ---------------- chain block ----------------
    u16* zone = KlZ;
    const int c = b - 2;                       // 0..509
    const int len = 32 + (c < 64 ? 1 : 0);     // 64x33 + 446x32 = 16384
    const int start = c*32 + (c < 64 ? c : 64);
    if(wave >= 4){                             // barrier-count match + store help
      __syncthreads(); __syncthreads();
      store_node(zone, Nbuf + (size_t)c*4096, tid);
      return;
    }
    const int w = wave;
    int sv = (lane < len) ? seq[start + lane] : 0;
    // init: zone slice = Zt(K_s0) cols [w*16, w*16+16)  (same conversion as before)
    {
      int s0 = __shfl(sv, 0, 64);
      const float* p = K + (size_t)s0*4096 + lane*64 + w*16;
#pragma unroll
      for(int h = 0; h < 4; h++){
        float4 a = *(const float4*)(p + h*4);
        const int cc = w*16 + h*4;
        zone[swz(cc+0, lane)] = f2bf(a.x); zone[swz(cc+1, lane)] = f2bf(a.y);
        zone[swz(cc+2, lane)] = f2bf(a.z); zone[swz(cc+3, lane)] = f2bf(a.w);
      }
    }
    f32x4 C[4];
    short8 Aa[2][4], Ab[2][4];
    int Aw = 0, j = 1;
    ldKfrag(Aa, Kfrag, __shfl(sv, 1, 64), lane);
    while(true){
      if(j + 1 < len) ldKfrag(Ab, Kfrag, __shfl(sv, j + 1, 64), lane);
      slice_mfma(Aa, zone, w, m16, q, C);
      if(j == len - 1) break;
      { float s = 1.f;
        if((j & 7) == 7){ int e = expof(slice_max(C)); Aw += e; s = exp2i(-e); }
        write_CT_slice(zone, w, m16, q, C, s); }
      j++;
      if(j + 1 < len) ldKfrag(Aa, Kfrag, __shfl(sv, j + 1, 64), lane);
      slice_mfma(Ab, zone, w, m16, q, C);
      if(j == len - 1) break;
      { float s = 1.f;
        if((j & 7) == 7){ int e = expof(slice_max(C)); Aw += e; s = exp2i(-e); }
        write_CT_slice(zone, w, m16, q, C, s); }
      j++;
    }
    // unify exponents across slices: S = max_w(A_w + e_w) == global-renorm S
    int myS = Aw + expof(slice_max(C));
    exps[w] = myS;
    __syncthreads();
    int S = max(max(exps[0], exps[1]), max(exps[2], exps[3]));
    scatter_slice(zone, w, m16, q, C, exp2i(Aw - S));   // C * 2^(Aw-S) = true * 2^-S
    if(w == 0 && lane == 0) Sarr[c] = S;
    __syncthreads();
    store_node(zone, Nbuf + (size_t)c*4096, tid);
    return;
  }

  // ---------------- power block (b==0 right, b==1 left) — verbatim R4 ----------------
  const bool left = (b == 1);
  u16* zones = KlZ;
  u16* rhoZ  = KlZ + 8*4096;
  u16* zw = zones + wave*4096;
  short8 Kf[2][4];                              // dual-use: A-frags of K_a AND B-frags of K_a^T
  if(!left) ld_gK_frags (K + (size_t)wave*4096, m16, q, Kf);
  else      ld_gKT_frags(K + (size_t)wave*4096, m16, q, Kf);

  const int row = tid >> 3, k0 = (tid & 7)*8;
  const int rpos = row*64 + (((tid & 7) ^ (row & 7)) << 3);
  {
    short8 bb;
#pragma unroll
    for(int j = 0; j < 8; j++) bb[j] = (row == k0 + j) ? (short)f2bf(1.f/64.f) : (short)0;
    *(short8*)(rhoZ + rpos) = bb;
  }
  __syncthreads();
  const float S13 = 1.f/8192.f;        // fixed per-iter scale (lambda ~ 2^13)
#pragma unroll
  for(int it = 0; it < POWER_ITERS; it++){
    short8 Ar[2][4];
#pragma unroll
    for(int ks = 0; ks < 2; ks++)
#pragma unroll
      for(int t = 0; t < 4; t++) Ar[ks][t] = lds_frag(rhoZ, t*16 + m16, ks*32 + q*8);
    f32x4 C[4][4];
#pragma unroll
    for(int i = 0; i < 4; i++)
#pragma unroll
      for(int j = 0; j < 4; j++) C[i][j] = f32x4{0.f,0.f,0.f,0.f};
#pragma unroll
    for(int ks = 0; ks < 2; ks++)
#pragma unroll
      for(int i = 0; i < 4; i++)
#pragma unroll
        for(int j = 0; j < 4; j++)
          C[i][j] = mfma_bf16(Ar[ks][i], Kf[ks][j], C[i][j]);   // rho * Kdir^T
    write_CT_lds(zw, lane, C);
    short8 Bt[2][4];
#pragma unroll
    for(int ks = 0; ks < 2; ks++)
#pragma unroll
      for(int t = 0; t < 4; t++) Bt[ks][t] = lds_frag(zw, t*16 + m16, ks*32 + q*8);
#pragma unroll
    for(int i = 0; i < 4; i++)
#pragma unroll
      for(int j = 0; j < 4; j++) C[i][j] = f32x4{0.f,0.f,0.f,0.f};
#pragma unroll
    for(int ks = 0; ks < 2; ks++)
#pragma unroll
      for(int i = 0; i < 4; i++)
#pragma unroll
        for(int j = 0; j < 4; j++)
          C[i][j] = mfma_bf16(Kf[ks][i], Bt[ks][j], C[i][j]);   // Kdir * (..)^T
    write_CT_lds(zw, lane, C);
    __syncthreads();
    float v[8];
#pragma unroll
    for(int j2 = 0; j2 < 8; j2++) v[j2] = 0.f;
#pragma unroll
    for(int z = 0; z < 8; z++){
      short8 f = lds_frag(zones + z*4096, row, k0);
#pragma unroll
      for(int j2 = 0; j2 < 8; j2++) v[j2] += bf2f((u16)f[j2]);
    }
    if(it != POWER_ITERS - 1){
      u32x4 u = { pack2bf(v[0]*S13, v[1]*S13), pack2bf(v[2]*S13, v[3]*S13),
                  pack2bf(v[4]*S13, v[5]*S13), pack2bf(v[6]*S13, v[7]*S13) };
      *(short8*)(rhoZ + rpos) = __builtin_bit_cast(short8, u);
      __syncthreads();
    } else {
      float pd = (k0 <= row && row < k0 + 8) ? v[row - k0] : 0.f;
      for(int off = 32; off; off >>= 1) pd += __shfl_xor(pd, off, 64);
      if(lane == 0) redf[wave] = pd;
      __syncthreads();
      float tr = 0.f;
#pragma unroll
      for(int w = 0; w < 8; w++) tr += redf[w];
      float inv = 1.f/tr;
      float* ro = left ? rhoL : rhoR;
      f32x4 w0 = { v[0]*inv, v[1]*inv, v[2]*inv, v[3]*inv };
      f32x4 w1 = { v[4]*inv, v[5]*inv, v[6]*inv, v[7]*inv };
      *(f32x4*)(ro + row*64 + k0)     = w0;
      *(f32x4*)(ro + row*64 + k0 + 4) = w1;
      u32x4 u = { pack2bf(v[0]*inv, v[1]*inv), pack2bf(v[2]*inv, v[3]*inv),
                  pack2bf(v[4]*inv, v[5]*inv), pack2bf(v[6]*inv, v[7]*inv) };
      *(short8*)(rhoZ + rpos) = __builtin_bit_cast(short8, u);   // normalized bf16 in LDS
      __syncthreads();
    }
  }
  if(left){
    // lambda = tr(rho_l * sum_a K_a K_a^T); wave a handles K_a
    short8 Ka[2][4];
    ld_gK_frags(K + (size_t)wave*4096, m16, q, Ka);
    f32x4 G[4][4];
#pragma unroll
    for(int i = 0; i < 4; i++)
#pragma unroll
      for(int j = 0; j < 4; j++) G[i][j] = f32x4{0.f,0.f,0.f,0.f};
#pragma unroll
    for(int ks = 0; ks < 2; ks++)
#pragma unroll
      for(int i = 0; i < 4; i++)
#pragma unroll
        for(int j = 0; j < 4; j++)
          G[i][j] = mfma_bf16(Ka[ks][i], Ka[ks][j], G[i][j]);
    float lp = 0.f;
#pragma unroll
    for(int i = 0; i < 4; i++)
#pragma unroll
      for(int j = 0; j < 4; j++)
#pragma unroll
        for(int t = 0; t < 4; t++){
          int r = i*16 + q*4 + t, c = j*16 + m16;
          lp += G[i][j][t] * bf2f(rhoZ[swz(r, c)]);
        }
    for(int off = 32; off; off >>= 1) lp += __shfl_xor(lp, off, 64);
    if(lane == 0) redf[wave] = lp;
    __syncthreads();
    if(tid == 0){
      float m = 0.f;
#pragma unroll
      for(int w = 0; w < 8; w++) m += redf[w];
      muv[0] = m;
    }
  }
}

// ==================== k_red: 256-thread blocks (4 slice waves), chain up to 8 nodes ====================
__global__ void __launch_bounds__(256) k_red(const u16* __restrict__ in, const int* __restrict__ Ein,
                                             u16* __restrict__ out, int* __restrict__ Eout, int total){
  __shared__ __align__(16) u16 zone[4096];
  __shared__ int exps[4];
  const int tid = threadIdx.x, lane = tid & 63, w = tid >> 6, b = blockIdx.x;
  const int m16 = lane & 15, q = lane >> 4;
  const int n0 = b*8;
  const int cnt = min(8, total - n0);

  // init: zone slice = Zt(node n0) cols [w*16, w*16+16)
  {
    const u16* N = in + (size_t)n0*4096;
    short8 v0 = *(const short8*)(N + lane*64 + w*16);
    short8 v1 = *(const short8*)(N + lane*64 + w*16 + 8);
#pragma unroll
    for(int e = 0; e < 8; e++){
      zone[swz(w*16 + e,     lane)] = (u16)v0[e];
      zone[swz(w*16 + 8 + e, lane)] = (u16)v1[e];
    }
  }
  f32x4 C[4];
  short8 Aa[2][4], Ab[2][4];
  int j = 1;
  ld_bf16_frags(in + (size_t)(n0 + 1)*4096, m16, q, Aa);
  while(true){
    if(j + 1 < cnt) ld_bf16_frags(in + (size_t)(n0 + j + 1)*4096, m16, q, Ab);
    slice_mfma(Aa, zone, w, m16, q, C);
    if(j == cnt - 1) break;
    write_CT_slice(zone, w, m16, q, C, 1.f);
    j++;
    if(j + 1 < cnt) ld_bf16_frags(in + (size_t)(n0 + j + 1)*4096, m16, q, Aa);
    slice_mfma(Ab, zone, w, m16, q, C);
    if(j == cnt - 1) break;
    write_CT_slice(zone, w, m16, q, C, 1.f);
    j++;
  }
  exps[w] = expof(slice_max(C));
  __syncthreads();
  int S = max(max(exps[0], exps[1]), max(exps[2], exps[3]));
  scatter_slice(zone, w, m16, q, C, exp2i(-S));
  __syncthreads();
  { // store (256 threads: 32B each)
    int row = tid >> 2, k0 = (tid & 3)*16;
    *(short8*)(out + (size_t)b*4096 + row*64 + k0)     = lds_frag(zone, row, k0);
    *(short8*)(out + (size_t)b*4096 + row*64 + k0 + 8) = lds_frag(zone, row, k0 + 8);
  }
  int sacc = (lane < cnt) ? Ein[n0 + lane] : 0;
  for(int off = 32; off; off >>= 1) sacc += __shfl_xor(sacc, off, 64);
  if(tid == 0) Eout[b] = S + sacc;
}

// ==================== K4: 1 block x 256 threads — split chain of 8 + contraction ====================
__global__ void __launch_bounds__(256) k4(const u16* __restrict__ M3, const int* __restrict__ E3,
                                          const float* __restrict__ rhoR, const float* __restrict__ rhoL,
                                          const float* __restrict__ muv, float* __restrict__ outp){
  __shared__ __align__(16) u16 Z[5*4096];  // 0: chain zone, 1: Pm (M Zn), 2: U^T, 3: rhoL Zn, 4: rhoR Zn
  __shared__ int exps[4];
  const int tid = threadIdx.x, lane = tid & 63, w = tid >> 6;
  const int m16 = lane & 15, q = lane >> 4;
  u16* zone = Z;
  u16* Pm   = Z + 4096;
  u16* z2   = Z + 2*4096;
  u16* zl   = Z + 3*4096;
  u16* zr   = Z + 4*4096;

  // ---- split chain of the 8 level-3 nodes ----
  {
    short8 v0 = *(const short8*)(M3 + lane*64 + w*16);
    short8 v1 = *(const short8*)(M3 + lane*64 + w*16 + 8);
#pragma unroll
    for(int e = 0; e < 8; e++){
      zone[swz(w*16 + e,     lane)] = (u16)v0[e];
      zone[swz(w*16 + 8 + e, lane)] = (u16)v1[e];
    }
  }
  f32x4 C[4];
  short8 Aa[2][4], Ab[2][4];
  int j = 1;
  ld_bf16_frags(M3 + (size_t)4096, m16, q, Aa);
  while(true){
    if(j + 1 < 8) ld_bf16_frags(M3 + (size_t)(j + 1)*4096, m16, q, Ab);
    slice_mfma(Aa, zone, w, m16, q, C);
    if(j == 7) break;
    write_CT_slice(zone, w, m16, q, C, 1.f);
    j++;
    if(j + 1 < 8) ld_bf16_frags(M3 + (size_t)(j + 1)*4096, m16, q, Aa);
    slice_mfma(Ab, zone, w, m16, q, C);
    if(j == 7) break;
    write_CT_slice(zone, w, m16, q, C, 1.f);
    j++;
  }
  exps[w] = expof(slice_max(C));
  __syncthreads();
  const int eM = max(max(exps[0], exps[1]), max(exps[2], exps[3]));
  scatter_slice(Pm, w, m16, q, C, exp2i(-eM));     // M (Zn)
  __syncthreads();
  if(w != 0) return;

  // ---- wave 0: contraction (verbatim R4 tail) ----
  // stage rho_r / rho_l fp32 -> Zn bf16 (lane owns row = lane)
#pragma unroll
  for(int g = 0; g < 8; g++){
    const float* p = rhoR + lane*64 + g*8;
    float4 a = *(const float4*)p, c = *(const float4*)(p + 4);
    u32x4 u = { pack2bf(a.x,a.y), pack2bf(a.z,a.w), pack2bf(c.x,c.y), pack2bf(c.z,c.w) };
    *(short8*)(zr + lane*64 + ((g ^ (lane & 7)) << 3)) = __builtin_bit_cast(short8, u);
  }
#pragma unroll
  for(int g = 0; g < 8; g++){
    const float* p = rhoL + lane*64 + g*8;
    float4 a = *(const float4*)p, c = *(const float4*)(p + 4);
    u32x4 u = { pack2bf(a.x,a.y), pack2bf(a.z,a.w), pack2bf(c.x,c.y), pack2bf(c.z,c.w) };
    *(short8*)(zl + lane*64 + ((g ^ (lane & 7)) << 3)) = __builtin_bit_cast(short8, u);
  }

  // t2 = sum rho_r o rho_l (fp32, from global)
  float t2 = 0.f;
  for(int j2 = 0; j2 < 64; j2++){
    int idx = lane + 64*j2;
    t2 += rhoR[idx] * rhoL[idx];
  }
  for(int off = 32; off; off >>= 1) t2 += __shfl_xor(t2, off, 64);

  // S = sum E3 + eM
  int sacc = (lane < 8) ? E3[lane] : 0;
  for(int off = 32; off; off >>= 1) sacc += __shfl_xor(sacc, off, 64);

  // U = M * rho_r -> U^T in z2   (rho symmetric: Zn A-pattern reads == B-frags)
  f32x4 D[4][4];
  short8 Ua[2][4], Ub[2][4];
  ld_zn_frags(Pm, m16, q, Ua);
  ld_zn_frags(zr, m16, q, Ub);
#pragma unroll
  for(int i = 0; i < 4; i++)
#pragma unroll
    for(int j2 = 0; j2 < 4; j2++) D[i][j2] = f32x4{0.f,0.f,0.f,0.f};
#pragma unroll
  for(int ks = 0; ks < 2; ks++)
#pragma unroll
    for(int i = 0; i < 4; i++)
#pragma unroll
      for(int j2 = 0; j2 < 4; j2++)
        D[i][j2] = mfma_bf16(Ua[ks][i], Ub[ks][j2], D[i][j2]);
  write_CT_lds(z2, lane, D);

  // D2 = rho_l * U
  ld_zn_frags(zl, m16, q, Ua);
#pragma unroll
  for(int ks = 0; ks < 2; ks++)
#pragma unroll
    for(int t = 0; t < 4; t++) Ub[ks][t] = lds_frag(z2, t*16 + m16, ks*32 + q*8);
#pragma unroll
  for(int i = 0; i < 4; i++)
#pragma unroll
    for(int j2 = 0; j2 < 4; j2++) D[i][j2] = f32x4{0.f,0.f,0.f,0.f};
#pragma unroll
  for(int ks = 0; ks < 2; ks++)
#pragma unroll
    for(int i = 0; i < 4; i++)
#pragma unroll
      for(int j2 = 0; j2 < 4; j2++)
        D[i][j2] = mfma_bf16(Ua[ks][i], Ub[ks][j2], D[i][j2]);

  // t1 = sum_ij D2_ij * M_ij
  float part = 0.f;
#pragma unroll
  for(int i = 0; i < 4; i++)
#pragma unroll
    for(int j2 = 0; j2 < 4; j2++)
#pragma unroll
      for(int t = 0; t < 4; t++){
        int r = i*16 + q*4 + t, c = j2*16 + m16;
        part += D[i][j2][t] * bf2f(Pm[swz(r, c)]);
      }
  for(int off = 32; off; off >>= 1) part += __shfl_xor(part, off, 64);
  if(lane == 0){
    double t1  = (double)part;
    double lam = (double)muv[0];
    double S   = (double)sacc + eM;
    double logp = 16384.0*log2(lam) - 2.0*S - log2(t1) + log2((double)t2);
    outp[0] = (float)logp;
  }
}

// ---------- launch: five stream-ordered kernels ----------
extern "C" void kernel_launch(void* const* d_in, const int* in_sizes, int n_in,
                              void* d_out, int out_size, void* d_ws, size_t ws_size,
                              hipStream_t stream) {
  const float* K  = (const float*)d_in[0];   // (8,64,64) fp32
  const int* seq  = (const int*)d_in[1];     // (16384,) int32
  char* ws = (char*)d_ws;
  u16*   Nbuf = (u16*)(ws);                    // 510 * 8KB = 4,177,920
  u16*   M2   = (u16*)(ws + 4177920);          // 64 * 8KB
  u16*   M3   = (u16*)(ws + 4702208);          // 8 * 8KB
  int*   Sarr = (int*)(ws + 4767744);          // 510 ints
  int*   E2   = (int*)(ws + 4771840);          // 64 ints
  int*   E3   = (int*)(ws + 4772096);          // 8 ints
  float* rhoR = (float*)(ws + 4772352);        // 16 KB
  float* rhoL = (float*)(ws + 4788736);        // 16 KB
  float* muv  = (float*)(ws + 4805120);        // 1 float
  u16*   Kfrag= (u16*)(ws + 4805184);          // 64 KB bf16 A-frag table

  kprep<<<  1, 512, 0, stream>>>(K, Kfrag);
  k1   <<<512, 512, 0, stream>>>(K, Kfrag, seq, Nbuf, Sarr, rhoR, rhoL, muv);
  k_red<<< 64, 256, 0, stream>>>(Nbuf, Sarr, M2, E2, 510);
  k_red<<<  8, 256, 0, stream>>>(M2, E2, M3, E3, 64);
  k4   <<<  1, 256, 0, stream>>>(M3, E3, rhoR, rhoL, muv, (float*)d_out);
}

// Round 6
// 99.907 us; speedup vs baseline: 1.3447x; 1.1936x over previous
//
#include <hip/hip_runtime.h>

typedef unsigned short u16;
typedef unsigned int   u32;
typedef short  short8  __attribute__((ext_vector_type(8)));
typedef __bf16 bf16x8  __attribute__((ext_vector_type(8)));
typedef float  f32x4   __attribute__((ext_vector_type(4)));
typedef u32    u32x4   __attribute__((ext_vector_type(4)));

#define POWER_ITERS 3

// ---------- helpers ----------
__device__ __forceinline__ u16 f2bf(float f){ return __builtin_bit_cast(u16, (__bf16)f); }
__device__ __forceinline__ u32 pack2bf(float a, float b){
  return (u32)__builtin_bit_cast(u16, (__bf16)a) | ((u32)__builtin_bit_cast(u16, (__bf16)b) << 16);
}
__device__ __forceinline__ float bf2f(u16 h){ return __uint_as_float(((u32)h) << 16); }

// write-through agent-scope store: data visible at coherence point on retirement
// (no buffer_wbl2 needed on the release side)
__device__ __forceinline__ void st_u32(u32* p, u32 v){
  __hip_atomic_store(p, v, __ATOMIC_RELAXED, __HIP_MEMORY_SCOPE_AGENT);
}
__device__ __forceinline__ void st_f32(float* p, float v){
  __hip_atomic_store(p, v, __ATOMIC_RELAXED, __HIP_MEMORY_SCOPE_AGENT);
}
__device__ __forceinline__ void st_i32(int* p, int v){
  __hip_atomic_store(p, v, __ATOMIC_RELAXED, __HIP_MEMORY_SCOPE_AGENT);
}

__device__ __forceinline__ f32x4 mfma_bf16(short8 a, short8 b, f32x4 c){
  return __builtin_amdgcn_mfma_f32_16x16x32_bf16(
      __builtin_bit_cast(bf16x8, a), __builtin_bit_cast(bf16x8, b), c, 0, 0, 0);
}

// swizzled LDS address (u16 units) of element [row][k] of a 64x64 matrix
__device__ __forceinline__ int swz(int row, int k){
  return row*64 + ((((k >> 3) ^ (row & 7)) << 3) | (k & 7));
}
__device__ __forceinline__ short8 lds_frag(const u16* P, int row, int k0){
  int pos = (k0 >> 3) ^ (row & 7);
  return *(const short8*)(P + row*64 + pos*8);
}
__device__ __forceinline__ short8 g_frag(const u16* __restrict__ M, int row, int k0){
  return *(const short8*)(M + row*64 + k0);
}

// write C/D regs (matrix X) as X^T into swizzled LDS (Zt), scaled
__device__ __forceinline__ void write_CT_lds_s(u16* Pt, int lane, const f32x4 (&C)[4][4], float s){
  const int m16 = lane & 15, q = lane >> 4;
#pragma unroll
  for(int i = 0; i < 4; i++){
    const int r0 = i*16 + q*4;
#pragma unroll
    for(int j = 0; j < 4; j++){
      const int c = j*16 + m16;
      const int addr = c*64 + ((((r0 >> 3) ^ (c & 7)) << 3) | (r0 & 7));
      u32 lo = pack2bf(C[i][j][0]*s, C[i][j][1]*s);
      u32 hi = pack2bf(C[i][j][2]*s, C[i][j][3]*s);
      *(uint2*)(Pt + addr) = make_uint2(lo, hi);
    }
  }
}
__device__ __forceinline__ void write_CT_lds(u16* Pt, int lane, const f32x4 (&C)[4][4]){
  write_CT_lds_s(Pt, lane, C, 1.f);
}

// write C ROW-MAJOR swizzled (Zn), scaled — scalar scatter
__device__ __forceinline__ void scatter_C_rm(u16* Z, int lane, const f32x4 (&C)[4][4], float s){
  const int m16 = lane & 15, q = lane >> 4;
#pragma unroll
  for(int i = 0; i < 4; i++)
#pragma unroll
    for(int j = 0; j < 4; j++)
#pragma unroll
      for(int t = 0; t < 4; t++)
        Z[swz(i*16 + q*4 + t, j*16 + m16)] = f2bf(C[i][j][t]*s);
}

// C = A (regs) * P (Pt = Zt of P); optional writeback of C^T into Pt
__device__ __forceinline__ void chain_step_A(const short8 (&Af)[2][4], u16* Pt, int lane,
                                             f32x4 (&C)[4][4], bool wb){
  const int m16 = lane & 15, q = lane >> 4;
  short8 Bf[2][4];
#pragma unroll
  for(int ks = 0; ks < 2; ks++)
#pragma unroll
    for(int t = 0; t < 4; t++) Bf[ks][t] = lds_frag(Pt, t*16 + m16, ks*32 + q*8);
#pragma unroll
  for(int i = 0; i < 4; i++)
#pragma unroll
    for(int j = 0; j < 4; j++) C[i][j] = f32x4{0.f,0.f,0.f,0.f};
#pragma unroll
  for(int ks = 0; ks < 2; ks++)
#pragma unroll
    for(int i = 0; i < 4; i++)
#pragma unroll
      for(int j = 0; j < 4; j++)
        C[i][j] = mfma_bf16(Af[ks][i], Bf[ks][j], C[i][j]);
  if(wb) write_CT_lds(Pt, lane, C);
}

__device__ __forceinline__ void ld_zn_frags(const u16* Zn, int m16, int q, short8 (&Af)[2][4]){
#pragma unroll
  for(int ks = 0; ks < 2; ks++)
#pragma unroll
    for(int t = 0; t < 4; t++) Af[ks][t] = lds_frag(Zn, t*16 + m16, ks*32 + q*8);
}
__device__ __forceinline__ void ld_bf16_frags(const u16* __restrict__ M, int m16, int q, short8 (&Af)[2][4]){
#pragma unroll
  for(int ks = 0; ks < 2; ks++)
#pragma unroll
    for(int t = 0; t < 4; t++) Af[ks][t] = g_frag(M, t*16 + m16, ks*32 + q*8);
}

// P = N (global row-major bf16) -> Zt of P
__device__ __forceinline__ void load_Pt_transpose(const u16* __restrict__ N, u16* Pt, int lane){
#pragma unroll
  for(int g = 0; g < 8; g++){
    short8 v = *(const short8*)(N + lane*64 + g*8);
#pragma unroll
    for(int t = 0; t < 8; t++) Pt[swz(g*8 + t, lane)] = (u16)v[t];
  }
}
// Pt <- Zt of an LDS Zn zone
__device__ __forceinline__ void lds_transpose(const u16* Z, u16* Pt, int lane){
#pragma unroll
  for(int g = 0; g < 8; g++){
    short8 f = lds_frag(Z, lane, g*8);
#pragma unroll
    for(int j = 0; j < 8; j++) Pt[swz(g*8 + j, lane)] = (u16)f[j];
  }
}

__device__ __forceinline__ float wave_max(float mx){
  for(int off = 32; off; off >>= 1) mx = fmaxf(mx, __shfl_xor(mx, off, 64));
  return mx;
}
__device__ __forceinline__ int norm_es(const f32x4 (&C)[4][4], float& s){
  float mx = 0.f;
#pragma unroll
  for(int i = 0; i < 4; i++)
#pragma unroll
    for(int j = 0; j < 4; j++)
#pragma unroll
      for(int t = 0; t < 4; t++) mx = fmaxf(mx, C[i][j][t]);   // entries all positive
  mx = wave_max(mx);
  int e; (void)frexpf(mx, &e);
  s = ldexpf(1.f, -e);
  return e;
}

// ---------- fence-free barriers ----------
// producer payloads go out via write-through atomic stores (st_u32), so arrive needs
// NO __threadfence (no buffer_wbl2). __syncthreads drains vmcnt => stores complete.
__device__ __forceinline__ void arrive(int* c){
  __syncthreads();
  if(threadIdx.x == 0)
    __hip_atomic_fetch_add(c, 1, __ATOMIC_RELAXED, __HIP_MEMORY_SCOPE_AGENT);
}
// consumer: acquire poll (buffer_inv only — no writeback)
__device__ __forceinline__ void wait_ge(int* c, int target){
  if(threadIdx.x == 0){
    while(__hip_atomic_load(c, __ATOMIC_ACQUIRE, __HIP_MEMORY_SCOPE_AGENT) < target)
      __builtin_amdgcn_s_sleep(2);
  }
  __syncthreads();
}

// store a 64x64 node from LDS (Zn swizzled) to global via write-through dword stores
__device__ __forceinline__ void store_node_wt(const u16* Z, u16* __restrict__ out, int tid){
  int row = tid >> 3, c0 = (tid & 7)*8;
  short8 v = lds_frag(Z, row, c0);
  u32x4 uv = __builtin_bit_cast(u32x4, v);
  u32* p = (u32*)(out + row*64 + c0);
#pragma unroll
  for(int i = 0; i < 4; i++) st_u32(p + i, uv[i]);
}

// ==================== single kernel: 256 blocks x 512 threads, 1 block/CU ====================
// Block b processes seq chunk sig(b) = (b&15)*16 + (b>>4)  (XCD-local groups).
// Blocks 254,255: power iteration after phase A. Blocks 0..15: group combiners.
// Block 0: final 16->1 + contraction.
__global__ __launch_bounds__(512) void kall(const float* __restrict__ K, const int* __restrict__ seq,
                                            u16* __restrict__ Nbuf, u16* __restrict__ M2buf,
                                            int* __restrict__ Sarr, int* __restrict__ Earr,
                                            float* __restrict__ rhoR, float* __restrict__ rhoL,
                                            float* __restrict__ muv, int* __restrict__ bar,
                                            float* __restrict__ outp){
  __shared__ __align__(16) u16 Kl[8*4096];     // bf16 K (Zn swizzled)
  __shared__ __align__(16) u16 zones[8*4096];
  __shared__ __align__(16) u16 rhoZ[4096];
  __shared__ float redf[8];
  __shared__ int exps[8];
  __shared__ float sh_t2;
  __shared__ int sh_S;
  const int tid = threadIdx.x, lane = tid & 63, wave = tid >> 6, b = blockIdx.x;
  const int m16 = lane & 15, q = lane >> 4;
  const int sig = (b & 15)*16 + (b >> 4);
  u16* zw = zones + wave*4096;

  // stage K[wave] fp32 -> Kl (Zn swizzled); lane owns row = lane
#pragma unroll
  for(int g = 0; g < 8; g++){
    const float* p = K + (size_t)wave*4096 + lane*64 + g*8;
    float4 a = *(const float4*)p, c = *(const float4*)(p + 4);
    u32x4 u = { pack2bf(a.x,a.y), pack2bf(a.z,a.w), pack2bf(c.x,c.y), pack2bf(c.z,c.w) };
    *(short8*)(Kl + wave*4096 + lane*64 + ((g ^ (lane & 7)) << 3)) = __builtin_bit_cast(short8, u);
  }
  int sv = (lane < 8) ? seq[sig*64 + wave*8 + lane] : 0;
  __syncthreads();

  // ================= PHASE A (all 256 blocks): node sig = 64 seq-mats =================
  {
    int s0 = __shfl(sv, 0, 64);
    lds_transpose(Kl + s0*4096, zw, lane);
    f32x4 C[4][4];
    short8 Af[2][4];
#pragma unroll 1
    for(int j = 1; j < 8; j++){
      int sj = __shfl(sv, j, 64);
      ld_zn_frags(Kl + sj*4096, m16, q, Af);
      chain_step_A(Af, zw, lane, C, j < 7);
    }
    { float s; int e = norm_es(C, s);
      if(!(wave & 1)) write_CT_lds_s(zw, lane, C, s);   // even wave -> Zt
      else            scatter_C_rm(zw, lane, C, s);     // odd wave  -> Zn
      if(lane == 0) exps[wave] = e; }
    __syncthreads();
    if(wave < 4){                                  // combine L1
      short8 Aa[2][4]; f32x4 Y[4][4];
      ld_zn_frags(zones + (2*wave + 1)*4096, m16, q, Aa);
      bool e2 = !(wave & 1);
      chain_step_A(Aa, zones + 2*wave*4096, lane, Y, e2);
      if(!e2) scatter_C_rm(zones + 2*wave*4096, lane, Y, 1.f);
    }
    __syncthreads();
    if(wave < 2){                                  // combine L2
      short8 Aa[2][4]; f32x4 Y[4][4];
      ld_zn_frags(zones + (4*wave + 2)*4096, m16, q, Aa);
      chain_step_A(Aa, zones + 4*wave*4096, lane, Y, wave == 0);
      if(wave == 1) scatter_C_rm(zones + 4*4096, lane, Y, 1.f);
    }
    __syncthreads();
    if(wave == 0){                                 // combine L3 + norm
      short8 Aa[2][4]; f32x4 M[4][4];
      ld_zn_frags(zones + 4*4096, m16, q, Aa);
      chain_step_A(Aa, zones, lane, M, false);
      float sr; int er = norm_es(M, sr);
      scatter_C_rm(zones, lane, M, sr);
      if(lane == 0){
        int ss = er;
#pragma unroll
        for(int w = 0; w < 8; w++) ss += exps[w];
        st_i32(&Sarr[sig], ss);
      }
    }
    __syncthreads();
    store_node_wt(zones, Nbuf + (size_t)sig*4096, tid);
  }
  arrive(bar + (b & 15)*16);                       // c1[group], sharded

  if(b >= 254){
    // ================= POWER (254=right, 255=left; parallel with combines) =================
    const bool left = (b == 255);
    short8 Kf[2][4];
    if(!left){
      ld_zn_frags(Kl + wave*4096, m16, q, Kf);
    } else {
#pragma unroll
      for(int ks = 0; ks < 2; ks++)
#pragma unroll
        for(int t = 0; t < 4; t++){
          short8 v;
#pragma unroll
          for(int j = 0; j < 8; j++) v[j] = (short)Kl[wave*4096 + swz(ks*32 + q*8 + j, t*16 + m16)];
          Kf[ks][t] = v;
        }
    }
    const int row = tid >> 3, k0 = (tid & 7)*8;
    const int rpos = row*64 + (((tid & 7) ^ (row & 7)) << 3);
    {
      short8 bb;
#pragma unroll
      for(int j = 0; j < 8; j++) bb[j] = (row == k0 + j) ? (short)f2bf(1.f/64.f) : (short)0;
      *(short8*)(rhoZ + rpos) = bb;
    }
    __syncthreads();
    const float S13 = 1.f/8192.f;        // fixed per-iter scale (lambda ~ 2^13)
#pragma unroll
    for(int it = 0; it < POWER_ITERS; it++){
      short8 Ar[2][4];
#pragma unroll
      for(int ks = 0; ks < 2; ks++)
#pragma unroll
        for(int t = 0; t < 4; t++) Ar[ks][t] = lds_frag(rhoZ, t*16 + m16, ks*32 + q*8);
      f32x4 C[4][4];
#pragma unroll
      for(int i = 0; i < 4; i++)
#pragma unroll
        for(int j = 0; j < 4; j++) C[i][j] = f32x4{0.f,0.f,0.f,0.f};
#pragma unroll
      for(int ks = 0; ks < 2; ks++)
#pragma unroll
        for(int i = 0; i < 4; i++)
#pragma unroll
          for(int j = 0; j < 4; j++)
            C[i][j] = mfma_bf16(Ar[ks][i], Kf[ks][j], C[i][j]);   // rho * Kdir^T
      write_CT_lds(zw, lane, C);
      short8 Bt[2][4];
#pragma unroll
      for(int ks = 0; ks < 2; ks++)
#pragma unroll
        for(int t = 0; t < 4; t++) Bt[ks][t] = lds_frag(zw, t*16 + m16, ks*32 + q*8);
#pragma unroll
      for(int i = 0; i < 4; i++)
#pragma unroll
        for(int j = 0; j < 4; j++) C[i][j] = f32x4{0.f,0.f,0.f,0.f};
#pragma unroll
      for(int ks = 0; ks < 2; ks++)
#pragma unroll
        for(int i = 0; i < 4; i++)
#pragma unroll
          for(int j = 0; j < 4; j++)
            C[i][j] = mfma_bf16(Kf[ks][i], Bt[ks][j], C[i][j]);   // Kdir * (..)^T
      write_CT_lds(zw, lane, C);
      __syncthreads();
      float v[8];
#pragma unroll
      for(int j2 = 0; j2 < 8; j2++) v[j2] = 0.f;
#pragma unroll
      for(int z = 0; z < 8; z++){
        short8 f = lds_frag(zones + z*4096, row, k0);
#pragma unroll
        for(int j2 = 0; j2 < 8; j2++) v[j2] += bf2f((u16)f[j2]);
      }
      if(it != POWER_ITERS - 1){
        u32x4 u = { pack2bf(v[0]*S13, v[1]*S13), pack2bf(v[2]*S13, v[3]*S13),
                    pack2bf(v[4]*S13, v[5]*S13), pack2bf(v[6]*S13, v[7]*S13) };
        *(short8*)(rhoZ + rpos) = __builtin_bit_cast(short8, u);
        __syncthreads();
      } else {
        float pd = (k0 <= row && row < k0 + 8) ? v[row - k0] : 0.f;
        for(int off = 32; off; off >>= 1) pd += __shfl_xor(pd, off, 64);
        if(lane == 0) redf[wave] = pd;
        __syncthreads();
        float tr = 0.f;
#pragma unroll
        for(int w = 0; w < 8; w++) tr += redf[w];
        float inv = 1.f/tr;
        float* ro = left ? rhoL : rhoR;
#pragma unroll
        for(int j2 = 0; j2 < 8; j2++) st_f32(&ro[row*64 + k0 + j2], v[j2]*inv);
        u32x4 u = { pack2bf(v[0]*inv, v[1]*inv), pack2bf(v[2]*inv, v[3]*inv),
                    pack2bf(v[4]*inv, v[5]*inv), pack2bf(v[6]*inv, v[7]*inv) };
        *(short8*)(rhoZ + rpos) = __builtin_bit_cast(short8, u);   // normalized bf16 in LDS
        __syncthreads();
      }
    }
    if(left){
      // lambda = tr(rho_l * sum_a K_a K_a^T); wave a handles K_a
      short8 Ka[2][4];
      ld_zn_frags(Kl + wave*4096, m16, q, Ka);
      f32x4 G[4][4];
#pragma unroll
      for(int i = 0; i < 4; i++)
#pragma unroll
        for(int j = 0; j < 4; j++) G[i][j] = f32x4{0.f,0.f,0.f,0.f};
#pragma unroll
      for(int ks = 0; ks < 2; ks++)
#pragma unroll
        for(int i = 0; i < 4; i++)
#pragma unroll
          for(int j = 0; j < 4; j++)
            G[i][j] = mfma_bf16(Ka[ks][i], Ka[ks][j], G[i][j]);
      float lp = 0.f;
#pragma unroll
      for(int i = 0; i < 4; i++)
#pragma unroll
        for(int j = 0; j < 4; j++)
#pragma unroll
          for(int t = 0; t < 4; t++){
            int r = i*16 + q*4 + t, c = j*16 + m16;
            lp += G[i][j][t] * bf2f(rhoZ[swz(r, c)]);
          }
      for(int off = 32; off; off >>= 1) lp += __shfl_xor(lp, off, 64);
      if(lane == 0) redf[wave] = lp;
      __syncthreads();
      if(tid == 0){
        float m = 0.f;
#pragma unroll
        for(int w = 0; w < 8; w++) m += redf[w];
        st_f32(muv, m);
      }
    }
    arrive(bar + 256);                             // c2 (rho/mu published, write-through)
  }

  if(b < 16){
    // ================= COMBINE: group b's 16 nodes -> M2buf[b] =================
    wait_ge(bar + b*16, 16);
    const int nb = b*16;
    short8 Af[2][4];
    f32x4 C[4][4];
    ld_bf16_frags(Nbuf + (size_t)(nb + 2*wave + 1)*4096, m16, q, Af);
    load_Pt_transpose(Nbuf + (size_t)(nb + 2*wave)*4096, zw, lane);
    chain_step_A(Af, zw, lane, C, false);
    { float s; int e = norm_es(C, s);
      if(!(wave & 1)) write_CT_lds_s(zw, lane, C, s);
      else            scatter_C_rm(zw, lane, C, s);
      if(lane == 0) exps[wave] = e; }
    __syncthreads();
    if(wave < 4){
      short8 Aa[2][4]; f32x4 Y[4][4];
      ld_zn_frags(zones + (2*wave + 1)*4096, m16, q, Aa);
      bool e2 = !(wave & 1);
      chain_step_A(Aa, zones + 2*wave*4096, lane, Y, e2);
      if(!e2) scatter_C_rm(zones + 2*wave*4096, lane, Y, 1.f);
    }
    __syncthreads();
    if(wave < 2){
      short8 Aa[2][4]; f32x4 Y[4][4];
      ld_zn_frags(zones + (4*wave + 2)*4096, m16, q, Aa);
      chain_step_A(Aa, zones + 4*wave*4096, lane, Y, wave == 0);
      if(wave == 1) scatter_C_rm(zones + 4*4096, lane, Y, 1.f);
    }
    __syncthreads();
    if(wave == 0){
      short8 Aa[2][4]; f32x4 M[4][4];
      ld_zn_frags(zones + 4*4096, m16, q, Aa);
      chain_step_A(Aa, zones, lane, M, false);
      float sr; int er = norm_es(M, sr);
      scatter_C_rm(zones, lane, M, sr);
      if(lane == 0){
        int ss = er;
#pragma unroll
        for(int w = 0; w < 8; w++) ss += exps[w];
        st_i32(&Earr[b], ss);
      }
    }
    __syncthreads();
    store_node_wt(zones, M2buf + (size_t)b*4096, tid);
    arrive(bar + 256);                             // c2
  }

  if(b == 0){
    // ================= FINAL =================
    wait_ge(bar + 256, 18);                        // 16 combiners + 2 power blocks
    short8 Af[2][4];
    f32x4 C[4][4];
    ld_bf16_frags(M2buf + (size_t)(2*wave + 1)*4096, m16, q, Af);
    load_Pt_transpose(M2buf + (size_t)(2*wave)*4096, zw, lane);
    chain_step_A(Af, zw, lane, C, false);
    { float s; int e = norm_es(C, s);
      if(!(wave & 1)) write_CT_lds_s(zw, lane, C, s);
      else            scatter_C_rm(zw, lane, C, s);
      if(lane == 0) exps[wave] = e; }
    __syncthreads();
    // L1 (waves 0-3) + side jobs (waves 4,5,6)
    if(wave < 4){
      short8 Aa[2][4]; f32x4 Y[4][4];
      ld_zn_frags(zones + (2*wave + 1)*4096, m16, q, Aa);
      bool e2 = !(wave & 1);
      chain_step_A(Aa, zones + 2*wave*4096, lane, Y, e2);
      if(!e2) scatter_C_rm(zones + 2*wave*4096, lane, Y, 1.f);
    } else if(wave == 4){
      float t2 = 0.f;
      for(int j = 0; j < 64; j++){
        int idx = lane + 64*j;
        t2 += rhoR[idx] * rhoL[idx];
      }
      for(int off = 32; off; off >>= 1) t2 += __shfl_xor(t2, off, 64);
      if(lane == 0) sh_t2 = t2;
    } else if(wave == 5){
      int s = Sarr[lane] + Sarr[lane + 64] + Sarr[lane + 128] + Sarr[lane + 192];
      if(lane < 16) s += Earr[lane];
      for(int off = 32; off; off >>= 1) s += __shfl_xor(s, off, 64);
      if(lane == 0) sh_S = s;
    } else if(wave == 6){
      // rho_r fp32 -> rhoZ (Zn bf16; symmetric)
#pragma unroll
      for(int g = 0; g < 8; g++){
        const float* p = rhoR + lane*64 + g*8;
        float4 a = *(const float4*)p, c = *(const float4*)(p + 4);
        u32x4 u = { pack2bf(a.x,a.y), pack2bf(a.z,a.w), pack2bf(c.x,c.y), pack2bf(c.z,c.w) };
        *(short8*)(rhoZ + lane*64 + ((g ^ (lane & 7)) << 3)) = __builtin_bit_cast(short8, u);
      }
    }
    __syncthreads();
    // L2 (waves 0,1); wave2: rho_l -> zone3 (free after L1)
    if(wave < 2){
      short8 Aa[2][4]; f32x4 Y[4][4];
      ld_zn_frags(zones + (4*wave + 2)*4096, m16, q, Aa);
      chain_step_A(Aa, zones + 4*wave*4096, lane, Y, wave == 0);
      if(wave == 1) scatter_C_rm(zones + 4*4096, lane, Y, 1.f);
    } else if(wave == 2){
#pragma unroll
      for(int g = 0; g < 8; g++){
        const float* p = rhoL + lane*64 + g*8;
        float4 a = *(const float4*)p, c = *(const float4*)(p + 4);
        u32x4 u = { pack2bf(a.x,a.y), pack2bf(a.z,a.w), pack2bf(c.x,c.y), pack2bf(c.z,c.w) };
        *(short8*)(zones + 3*4096 + lane*64 + ((g ^ (lane & 7)) << 3)) = __builtin_bit_cast(short8, u);
      }
    }
    __syncthreads();
    // L3 + contraction (wave 0)
    if(wave == 0){
      short8 Aa[2][4];
      ld_zn_frags(zones + 4*4096, m16, q, Aa);
      chain_step_A(Aa, zones, lane, C, false);
      float sM; int eM = norm_es(C, sM);
      u16* Pm = zones + 1*4096;                    // free zone
      scatter_C_rm(Pm, lane, C, sM);               // M (Zn)

      // U = M * rho_r -> U^T in zone2
      short8 Ua[2][4], Ub[2][4];
      ld_zn_frags(Pm, m16, q, Ua);
      ld_zn_frags(rhoZ, m16, q, Ub);
#pragma unroll
      for(int i = 0; i < 4; i++)
#pragma unroll
        for(int j = 0; j < 4; j++) C[i][j] = f32x4{0.f,0.f,0.f,0.f};
#pragma unroll
      for(int ks = 0; ks < 2; ks++)
#pragma unroll
        for(int i = 0; i < 4; i++)
#pragma unroll
          for(int j = 0; j < 4; j++)
            C[i][j] = mfma_bf16(Ua[ks][i], Ub[ks][j], C[i][j]);
      write_CT_lds(zones + 2*4096, lane, C);

      // D2 = rho_l * U
      ld_zn_frags(zones + 3*4096, m16, q, Ua);
#pragma unroll
      for(int ks = 0; ks < 2; ks++)
#pragma unroll
        for(int t = 0; t < 4; t++) Ub[ks][t] = lds_frag(zones + 2*4096, t*16 + m16, ks*32 + q*8);
#pragma unroll
      for(int i = 0; i < 4; i++)
#pragma unroll
        for(int j = 0; j < 4; j++) C[i][j] = f32x4{0.f,0.f,0.f,0.f};
#pragma unroll
      for(int ks = 0; ks < 2; ks++)
#pragma unroll
        for(int i = 0; i < 4; i++)
#pragma unroll
          for(int j = 0; j < 4; j++)
            C[i][j] = mfma_bf16(Ua[ks][i], Ub[ks][j], C[i][j]);

      // t1 = sum_ij D2_ij * M_ij
      float part = 0.f;
#pragma unroll
      for(int i = 0; i < 4; i++)
#pragma unroll
        for(int j = 0; j < 4; j++)
#pragma unroll
          for(int t = 0; t < 4; t++){
            int r = i*16 + q*4 + t, c = j*16 + m16;
            part += C[i][j][t] * bf2f(Pm[swz(r, c)]);
          }
      for(int off = 32; off; off >>= 1) part += __shfl_xor(part, off, 64);
      if(lane == 0){
        double t1  = (double)part;
        double lam = (double)muv[0];
        double S   = (double)sh_S + eM;
#pragma unroll
        for(int w = 0; w < 8; w++) S += exps[w];
        double logp = 16384.0*log2(lam) - 2.0*S - log2(t1) + log2((double)sh_t2);
        outp[0] = (float)logp;
      }
    }
  }
}

// ---------- launch ----------
extern "C" void kernel_launch(void* const* d_in, const int* in_sizes, int n_in,
                              void* d_out, int out_size, void* d_ws, size_t ws_size,
                              hipStream_t stream) {
  const float* K  = (const float*)d_in[0];   // (8,64,64) fp32
  const int* seq  = (const int*)d_in[1];     // (16384,) int32
  char* ws = (char*)d_ws;
  u16*   Nbuf  = (u16*)(ws);                   // 256 * 8KB = 2 MB
  u16*   M2buf = (u16*)(ws + 2097152);         // 16 * 8KB = 128 KB
  int*   Sarr  = (int*)(ws + 2228224);         // 256 ints
  int*   Earr  = (int*)(ws + 2229248);         // 16 ints
  float* rhoR  = (float*)(ws + 2229760);       // 16 KB
  float* rhoL  = (float*)(ws + 2246144);       // 16 KB
  float* muv   = (float*)(ws + 2262528);       // 1 float
  int*   bar   = (int*)(ws + 2262592);         // c1[16] sharded (64B/line) + c2 at [256]

  hipMemsetAsync(bar, 0, (256 + 16)*4, stream);
  kall<<<256, 512, 0, stream>>>(K, seq, Nbuf, M2buf, Sarr, Earr, rhoR, rhoL, muv, bar,
                                (float*)d_out);
}